// Round 2
// baseline (151.027 us; speedup 1.0000x reference)
//
#include <hip/hip_runtime.h>

#define T_LEN 2048
#define NSTATE 64
#define NCHUNK 32
#define CH_S 64       // stored steps per chunk
#define WARM 64       // warm-up steps (10.7*mu) before the stored region
#define RK 16         // renorm every 16 steps (scale cancels in LLR)

// v_add_f32 with DPP-modified src: single fused VALU instr, no DS op.
template<int CTRL>
__device__ __forceinline__ float dpp_add(float v) {
    int r = __builtin_amdgcn_update_dpp(0, __float_as_int(v), CTRL, 0xF, 0xF, true);
    return v + __int_as_float(r);
}

// Pure-DPP 64-lane sum: row_shr 1,2,4,8 then row_bcast15, row_bcast31.
// Total lands in lane 63. Zero DS ops.
__device__ __forceinline__ float dpp_sum_to63(float v) {
    v = dpp_add<0x111>(v);   // row_shr:1
    v = dpp_add<0x112>(v);   // row_shr:2
    v = dpp_add<0x114>(v);   // row_shr:4
    v = dpp_add<0x118>(v);   // row_shr:8  -> lane 15/31/47/63 hold row sums
    v = dpp_add<0x142>(v);   // row_bcast15: lane31 = rows0+1, lane63 = rows2+3
    v = dpp_add<0x143>(v);   // row_bcast31: lane63 = all four rows
    return v;
}

// Full-wave sum broadcast to every lane via v_readlane (SGPR) — zero DS ops.
__device__ __forceinline__ float wave_total(float v) {
    float s = dpp_sum_to63(v);
    return __int_as_float(__builtin_amdgcn_readlane(__float_as_int(s), 63));
}

// v + v[lane^1] via DPP quad_perm [1,0,3,2] — VALU pipe, no DS op.
__device__ __forceinline__ float pair_sum_xor1(float v) {
    int r = __builtin_amdgcn_update_dpp(0, __float_as_int(v), 0xB1, 0xF, 0xF, true);
    return v + __int_as_float(r);
}

// cheap fp32 -> bf16 (round-half-up): 2 VALU ops
__device__ __forceinline__ unsigned short bf16_of(float f) {
    return (unsigned short)((__float_as_uint(f) + 0x8000u) >> 16);
}

// GEN_POLY = ('1111001','1011011'), mu=6, NS=64.
// State s: shift register, most-recent bit = MSB (bit 5).
// o0 parity mask of s: 57 ; o1 mask: 27.
// log2-domain branch metric: x_s = kE*la + (kE*c0)*l0 + (kE*c1)*l1, kE = 0.5*log2(e)
// gamma(s,0) = 2^x_s ; gamma(s,1) = 2^-x_s.
// to(s,b) = (b<<5) | (s>>1).

// ---------------- Kernel F: forward sweep, writes alpha_t (bf16) ----------------
__global__ __launch_bounds__(256, 8)
void bcjr_fwd_kernel(const float* __restrict__ llr_ch,   // [B][2*T]
                     const float* __restrict__ llr_a,    // [B][T]
                     unsigned short* __restrict__ wsA)   // [B][T][64] bf16 alpha_t
{
    const int wave  = blockIdx.x * 4 + (threadIdx.x >> 6);
    const int lane  = threadIdx.x & 63;
    const int chunk = wave & (NCHUNK - 1);
    const int b     = wave >> 5;

    const float c0 = 1.0f - 2.0f * (float)(__popc(lane & 57) & 1);
    const float c1 = 1.0f - 2.0f * (float)(__popc(lane & 27) & 1);
    const float kE = 0.5f * 1.442695040888963f;
    const float k0 = kE * c0, k1 = kE * c1;

    const float* chp = llr_ch + (size_t)b * (2 * T_LEN);
    const float* lap = llr_a  + (size_t)b * T_LEN;
    unsigned short* w = wsA + (size_t)b * T_LEN * NSTATE;

    const int  fs0 = 2 * (lane & 31);
    const bool fhi = (lane >= 32);
    const int t0 = chunk * CH_S;
    const int ts = (chunk == 0) ? t0 : t0 - WARM;
    float state = (chunk == 0) ? ((lane == 0) ? 1.0f : 0.0f) : (1.0f / 64.0f);

    for (int g = ts; g < t0 + CH_S; g += RK) {
        const bool store = (g >= t0);
        #pragma unroll
        for (int h = 0; h < 2; ++h) {
            const int gb = g + 8 * h;
            const float4* c4 = (const float4*)(chp + 2 * gb);
            const float4* a4 = (const float4*)(lap + gb);
            float4 cc[4], aa[2];
            #pragma unroll
            for (int i = 0; i < 4; ++i) cc[i] = c4[i];
            #pragma unroll
            for (int i = 0; i < 2; ++i) aa[i] = a4[i];
            unsigned short* wb = w + (size_t)gb * NSTATE + lane;
            #pragma unroll
            for (int i = 0; i < 8; ++i) {
                float l0 = (i & 1) ? cc[i >> 1].z : cc[i >> 1].x;
                float l1 = (i & 1) ? cc[i >> 1].w : cc[i >> 1].y;
                float la = ((const float*)aa)[i];
                if (store) wb[i * NSTATE] = bf16_of(state);   // alpha_t
                float x   = fmaf(la, kE, fmaf(l0, k0, l1 * k1));
                float g0v = exp2f(x);
                float g1v = __builtin_amdgcn_rcpf(g0v);
                float s0  = pair_sum_xor1(state * g0v);
                float s1  = pair_sum_xor1(state * g1v);
                float a0  = __shfl(s0, fs0, 64);
                float a1  = __shfl(s1, fs0, 64);
                state = fhi ? a1 : a0;
            }
        }
        float s = wave_total(state);
        state = state * __builtin_amdgcn_rcpf(s);
    }
}

// ---------------- Kernel G: backward sweep + fused LLR ----------------
// beta stays in registers (fp32, never stored). Per stored step:
//   p0 = gamma(s,0)*beta_next[to0(s)], p1 = gamma(s,1)*beta_next[to1(s)]
//   llr_t = ln(sum_s alpha_t[s]*p0) - ln(sum_s alpha_t[s]*p1)
// Dual reduction: two independent pure-DPP reduce-to-63 chains (12 fused
// v_add_f32_dpp, zero DS ops); log2 difference on lane 63, masked store.
__global__ __launch_bounds__(256, 8)
void bcjr_bwd_llr_kernel(const float* __restrict__ llr_ch,
                         const float* __restrict__ llr_a,
                         const unsigned short* __restrict__ wsA,
                         float* __restrict__ out)          // [B][T]
{
    const int wave  = blockIdx.x * 4 + (threadIdx.x >> 6);
    const int lane  = threadIdx.x & 63;
    const int chunk = wave & (NCHUNK - 1);
    const int b     = wave >> 5;

    const float c0 = 1.0f - 2.0f * (float)(__popc(lane & 57) & 1);
    const float c1 = 1.0f - 2.0f * (float)(__popc(lane & 27) & 1);
    const float kE = 0.5f * 1.442695040888963f;
    const float k0 = kE * c0, k1 = kE * c1;

    const float* chp = llr_ch + (size_t)b * (2 * T_LEN);
    const float* lap = llr_a  + (size_t)b * T_LEN;
    const unsigned short* wa = wsA + (size_t)b * T_LEN * NSTATE;
    float* outp = out + (size_t)b * T_LEN;

    const int  bs0 = lane >> 1;          // to0(s) = s>>1
    const int  bs1 = 32 + (lane >> 1);   // to1(s) = 32 + (s>>1)
    const int t0 = chunk * CH_S;
    const int te = (chunk == NCHUNK - 1) ? (t0 + CH_S) : (t0 + CH_S + WARM);
    float state = 1.0f / 64.0f;          // beta_T = 1/NS exactly for last chunk

    for (int g = te - RK; g >= t0; g -= RK) {
        const bool act = (g < t0 + CH_S);   // stored region: compute LLR
        #pragma unroll
        for (int h = 1; h >= 0; --h) {
            const int gb = g + 8 * h;
            const float4* c4 = (const float4*)(chp + 2 * gb);
            const float4* a4 = (const float4*)(lap + gb);
            float4 cc[4], aa[2];
            #pragma unroll
            for (int i = 0; i < 4; ++i) cc[i] = c4[i];
            #pragma unroll
            for (int i = 0; i < 2; ++i) aa[i] = a4[i];
            float av[8];
            if (act) {
                // alpha_t for the 8 steps: 128 B coalesced ushort loads, issued early
                const unsigned short* ap = wa + (size_t)gb * NSTATE + lane;
                #pragma unroll
                for (int i = 0; i < 8; ++i)
                    av[i] = __uint_as_float(((unsigned)ap[i * NSTATE]) << 16);
            }
            #pragma unroll
            for (int i = 7; i >= 0; --i) {
                float l0 = (i & 1) ? cc[i >> 1].z : cc[i >> 1].x;
                float l1 = (i & 1) ? cc[i >> 1].w : cc[i >> 1].y;
                float la = ((const float*)aa)[i];
                float x   = fmaf(la, kE, fmaf(l0, k0, l1 * k1));
                float g0v = exp2f(x);
                float g1v = __builtin_amdgcn_rcpf(g0v);
                float t0v = __shfl(state, bs0, 64);
                float t1v = __shfl(state, bs1, 64);
                float p0 = g0v * t0v;
                float p1 = g1v * t1v;
                if (act) {
                    float na = dpp_sum_to63(av[i] * p0);   // n0 total -> lane 63
                    float nb = dpp_sum_to63(av[i] * p1);   // n1 total -> lane 63
                    float d  = (__log2f(na) - __log2f(nb)) * 0.6931471805599453f;
                    if (lane == 63) outp[gb + i] = d;      // llr_t
                }
                state = p0 + p1;                           // beta_t
            }
        }
        float s = wave_total(state);
        state = state * __builtin_amdgcn_rcpf(s);
    }
}

extern "C" void kernel_launch(void* const* d_in, const int* in_sizes, int n_in,
                              void* d_out, int out_size, void* d_ws, size_t ws_size,
                              hipStream_t stream) {
    const float* llr_ch = (const float*)d_in[0];
    const float* llr_a  = (const float*)d_in[1];
    float* out = (float*)d_out;

    int B = in_sizes[0] / (2 * T_LEN);   // 256
    unsigned short* wsA = (unsigned short*)d_ws;  // [B][T][64] bf16, 64 MiB

    int n_waves = B * NCHUNK;            // 8192 waves per phase (full occupancy)
    hipLaunchKernelGGL(bcjr_fwd_kernel, dim3(n_waves / 4), dim3(256), 0, stream,
                       llr_ch, llr_a, wsA);
    hipLaunchKernelGGL(bcjr_bwd_llr_kernel, dim3(n_waves / 4), dim3(256), 0, stream,
                       llr_ch, llr_a, wsA, out);
}

// Round 3
// 141.436 us; speedup vs baseline: 1.0678x; 1.0678x over previous
//
#include <hip/hip_runtime.h>

#define T_LEN 2048
#define NSTATE 64
#define NCHUNK 32
#define CH_S 64       // stored steps per chunk = LDS buffer depth
#define WARM 64       // warm-up steps (10.7*mu) before/after the stored region
#define RK 16         // renorm every 16 steps (scale cancels in LLR)

// v_add_f32 with DPP-modified src: single fused VALU instr, no DS op.
template<int CTRL>
__device__ __forceinline__ float dpp_add(float v) {
    int r = __builtin_amdgcn_update_dpp(0, __float_as_int(v), CTRL, 0xF, 0xF, true);
    return v + __int_as_float(r);
}

// Pure-DPP 64-lane sum: row_shr 1,2,4,8 then row_bcast15, row_bcast31.
// Total lands in lane 63. Zero DS ops.
__device__ __forceinline__ float dpp_sum_to63(float v) {
    v = dpp_add<0x111>(v);   // row_shr:1
    v = dpp_add<0x112>(v);   // row_shr:2
    v = dpp_add<0x114>(v);   // row_shr:4
    v = dpp_add<0x118>(v);   // row_shr:8  -> lane 15/31/47/63 hold row sums
    v = dpp_add<0x142>(v);   // row_bcast15: lane31 = rows0+1, lane63 = rows2+3
    v = dpp_add<0x143>(v);   // row_bcast31: lane63 = all four rows
    return v;
}

// Full-wave sum broadcast to every lane via v_readlane (SGPR) — zero DS ops.
__device__ __forceinline__ float wave_total(float v) {
    float s = dpp_sum_to63(v);
    return __int_as_float(__builtin_amdgcn_readlane(__float_as_int(s), 63));
}

// v + v[lane^1] via DPP quad_perm [1,0,3,2] — VALU pipe, no DS op.
__device__ __forceinline__ float pair_sum_xor1(float v) {
    int r = __builtin_amdgcn_update_dpp(0, __float_as_int(v), 0xB1, 0xF, 0xF, true);
    return v + __int_as_float(r);
}

// cheap fp32 -> bf16 (round-half-up): 2 VALU ops
__device__ __forceinline__ unsigned short bf16_of(float f) {
    return (unsigned short)((__float_as_uint(f) + 0x8000u) >> 16);
}

// GEN_POLY = ('1111001','1011011'), mu=6, NS=64.
// State s: shift register, most-recent bit = MSB (bit 5).
// o0 parity mask of s: 57 ; o1 mask: 27.
// x_s = kE*la + (kE*c0)*l0 + (kE*c1)*l1, kE = 0.5*log2(e)
// gamma(s,0) = 2^x_s ; gamma(s,1) = 2^-x_s ; to(s,b) = (b<<5)|(s>>1).

// ---- fwd 16-step group (renorm at end); stores alpha_t into LDS when STORE ----
template<bool STORE>
__device__ __forceinline__ float fwd_group(float state,
                                           const float* __restrict__ chp,
                                           const float* __restrict__ lap,
                                           unsigned short* __restrict__ alds,
                                           int g, int t0, int lane,
                                           float kE, float k0, float k1,
                                           int fs0, bool fhi)
{
    #pragma unroll
    for (int h = 0; h < 2; ++h) {
        const int gb = g + 8 * h;
        const float4* c4 = (const float4*)(chp + 2 * gb);
        const float4* a4 = (const float4*)(lap + gb);
        float4 cc[4], aa[2];
        #pragma unroll
        for (int i = 0; i < 4; ++i) cc[i] = c4[i];
        #pragma unroll
        for (int i = 0; i < 2; ++i) aa[i] = a4[i];
        #pragma unroll
        for (int i = 0; i < 8; ++i) {
            float l0 = (i & 1) ? cc[i >> 1].z : cc[i >> 1].x;
            float l1 = (i & 1) ? cc[i >> 1].w : cc[i >> 1].y;
            float la = ((const float*)aa)[i];
            if (STORE) alds[(gb + i - t0) * NSTATE + lane] = bf16_of(state);
            float x   = fmaf(la, kE, fmaf(l0, k0, l1 * k1));
            float g0v = exp2f(x);
            float g1v = __builtin_amdgcn_rcpf(g0v);
            float s0  = pair_sum_xor1(state * g0v);
            float s1  = pair_sum_xor1(state * g1v);
            float a0  = __shfl(s0, fs0, 64);
            float a1  = __shfl(s1, fs0, 64);
            state = fhi ? a1 : a0;
        }
    }
    float s = wave_total(state);
    return state * __builtin_amdgcn_rcpf(s);
}

// ---- bwd 16-step group (renorm at end); fused LLR from LDS alpha when LLR ----
template<bool LLR>
__device__ __forceinline__ float bwd_group(float state,
                                           const float* __restrict__ chp,
                                           const float* __restrict__ lap,
                                           const unsigned short* __restrict__ alds,
                                           float* __restrict__ outp,
                                           int g, int t0, int lane,
                                           float kE, float k0, float k1,
                                           int bs0, int bs1)
{
    #pragma unroll
    for (int h = 1; h >= 0; --h) {
        const int gb = g + 8 * h;
        const float4* c4 = (const float4*)(chp + 2 * gb);
        const float4* a4 = (const float4*)(lap + gb);
        float4 cc[4], aa[2];
        #pragma unroll
        for (int i = 0; i < 4; ++i) cc[i] = c4[i];
        #pragma unroll
        for (int i = 0; i < 2; ++i) aa[i] = a4[i];
        float av[8];
        if (LLR) {
            // alpha_t for the 8 steps: ds_read_u16, 2 lanes/bank -> conflict-free
            #pragma unroll
            for (int i = 0; i < 8; ++i)
                av[i] = __uint_as_float(((unsigned)alds[(gb + i - t0) * NSTATE + lane]) << 16);
        }
        #pragma unroll
        for (int i = 7; i >= 0; --i) {
            float l0 = (i & 1) ? cc[i >> 1].z : cc[i >> 1].x;
            float l1 = (i & 1) ? cc[i >> 1].w : cc[i >> 1].y;
            float la = ((const float*)aa)[i];
            float x   = fmaf(la, kE, fmaf(l0, k0, l1 * k1));
            float g0v = exp2f(x);
            float g1v = __builtin_amdgcn_rcpf(g0v);
            float t0v = __shfl(state, bs0, 64);
            float t1v = __shfl(state, bs1, 64);
            float p0 = g0v * t0v;
            float p1 = g1v * t1v;
            if (LLR) {
                float na = dpp_sum_to63(av[i] * p0);   // n0 total -> lane 63
                float nb = dpp_sum_to63(av[i] * p1);   // n1 total -> lane 63
                float d  = (__log2f(na) - __log2f(nb)) * 0.6931471805599453f;
                if (lane == 63) outp[gb + i] = d;      // llr_t
            }
            state = p0 + p1;                           // beta_t
        }
    }
    float s = wave_total(state);
    return state * __builtin_amdgcn_rcpf(s);
}

// ---------------- Fused kernel: wave 0 = fwd (alpha -> LDS), wave 1 = bwd+LLR ----------------
// One barrier: fwd finishes all stores before bwd's stored region begins.
// bwd's warm-up runs concurrently with fwd. Zero global workspace.
__global__ __launch_bounds__(128, 8)
void bcjr_fused_kernel(const float* __restrict__ llr_ch,   // [B][2*T]
                       const float* __restrict__ llr_a,    // [B][T]
                       float* __restrict__ out)            // [B][T]
{
    __shared__ unsigned short alds[CH_S * NSTATE];   // 8 KiB: alpha for this chunk

    const int lane  = threadIdx.x & 63;
    const int role  = threadIdx.x >> 6;              // 0 = fwd, 1 = bwd+llr
    const int unit  = blockIdx.x;
    const int chunk = unit & (NCHUNK - 1);
    const int b     = unit >> 5;                     // unit / NCHUNK

    const float c0 = 1.0f - 2.0f * (float)(__popc(lane & 57) & 1);
    const float c1 = 1.0f - 2.0f * (float)(__popc(lane & 27) & 1);
    const float kE = 0.5f * 1.442695040888963f;
    const float k0 = kE * c0, k1 = kE * c1;

    const float* chp = llr_ch + (size_t)b * (2 * T_LEN);
    const float* lap = llr_a  + (size_t)b * T_LEN;
    const int t0 = chunk * CH_S;

    if (role == 0) {
        // ---- forward wave ----
        const int  fs0 = 2 * (lane & 31);
        const bool fhi = (lane >= 32);
        float state = (chunk == 0) ? ((lane == 0) ? 1.0f : 0.0f) : (1.0f / 64.0f);
        const int ts = (chunk == 0) ? t0 : t0 - WARM;
        for (int g = ts; g < t0; g += RK)
            state = fwd_group<false>(state, chp, lap, alds, g, t0, lane, kE, k0, k1, fs0, fhi);
        for (int g = t0; g < t0 + CH_S; g += RK)
            state = fwd_group<true>(state, chp, lap, alds, g, t0, lane, kE, k0, k1, fs0, fhi);
        __syncthreads();   // publish alpha; then this wave exits, freeing its slot
    } else {
        // ---- backward wave ----
        const int bs0 = lane >> 1;           // to0(s) = s>>1
        const int bs1 = 32 + (lane >> 1);    // to1(s) = 32 + (s>>1)
        float state = 1.0f / 64.0f;          // exact beta_T for the last chunk
        const int te = (chunk == NCHUNK - 1) ? (t0 + CH_S) : (t0 + CH_S + WARM);
        for (int g = te - RK; g >= t0 + CH_S; g -= RK)
            state = bwd_group<false>(state, chp, lap, alds, nullptr, g, t0, lane, kE, k0, k1, bs0, bs1);
        __syncthreads();   // wait for alpha
        float* outp = out + (size_t)b * T_LEN;
        for (int g = t0 + CH_S - RK; g >= t0; g -= RK)
            state = bwd_group<true>(state, chp, lap, alds, outp, g, t0, lane, kE, k0, k1, bs0, bs1);
    }
}

extern "C" void kernel_launch(void* const* d_in, const int* in_sizes, int n_in,
                              void* d_out, int out_size, void* d_ws, size_t ws_size,
                              hipStream_t stream) {
    const float* llr_ch = (const float*)d_in[0];
    const float* llr_a  = (const float*)d_in[1];
    float* out = (float*)d_out;

    int B = in_sizes[0] / (2 * T_LEN);   // 256
    (void)d_ws; (void)ws_size;           // no workspace needed anymore

    int n_units = B * NCHUNK;            // 8192 blocks (1 chunk each, 2 waves)
    hipLaunchKernelGGL(bcjr_fused_kernel, dim3(n_units), dim3(128), 0, stream,
                       llr_ch, llr_a, out);
}